// Round 3
// baseline (652.430 us; speedup 1.0000x reference)
//
#include <hip/hip_runtime.h>
#include <math.h>

#define ANUM 3
#define CNUM 3
#define BNUM 32
#define MNUM 16
#define CH 24      // ANUM*(5+CNUM)
#define NBIN 8192  // 13-bit float-top-bits histogram (sign=0 for all values)
#define NSEG 96
#define CAP 8192   // max in-threshold-bin candidates kept (worst real ~2K)
#define CHUNK 4800 // elements per k2_scan block; divides 76800/19200/4800
#define CPB 21     // chunks per batch image: 16 + 4 + 1

// All small state lives in static device memory -> workspace holds ONLY negvals.
__device__ __align__(16) int   g_hist[NSEG*NBIN];
__device__ __align__(16) float g_cand[(size_t)NSEG*CAP];
__device__ int   g_ccnt[NSEG];
__device__ int   g_T[NSEG];
__device__ int   g_kk[NSEG];
__device__ int   g_cab[NSEG];   // count strictly above bin T
__device__ float g_sab[NSEG];   // sum of values strictly above bin T
__device__ float g_acc[NSEG*5];
__device__ float g_lsum[3];

__device__ __forceinline__ float wred(float v){
  #pragma unroll
  for (int off=32; off; off>>=1) v += __shfl_down(v, off, 64);
  return v;
}

__global__ __launch_bounds__(256) void kinit(){
  const int gid = blockIdx.x*256 + threadIdx.x;   // 768*256 = 196608 threads
  ((int4*)g_hist)[gid] = make_int4(0,0,0,0);      // 196608*4 = NSEG*NBIN ints
  if (gid < NSEG*5) g_acc[gid] = 0.f;
  if (gid < 3) g_lsum[gid] = 0.f;
  if (gid < NSEG){ g_ccnt[gid]=0; g_sab[gid]=0.f; }
}

__global__ __launch_bounds__(256) void k1_scan(
    const float* __restrict__ pred, const float* __restrict__ boxes,
    const int* __restrict__ labels, float* __restrict__ negvals,
    int H, int W, int scale)
{
  const int b = blockIdx.y;
  const int N = H*W*ANUM;
  const int HW = H*W;
  const int n = blockIdx.x*256 + threadIdx.x;

  __shared__ float sbox[MNUM*4];
  __shared__ int slab[MNUM];
  if (threadIdx.x < MNUM*4) sbox[threadIdx.x] = boxes[b*MNUM*4 + threadIdx.x];
  else if (threadIdx.x < MNUM*5) slab[threadIdx.x - MNUM*4] = labels[b*MNUM + (threadIdx.x - MNUM*4)];
  __syncthreads();

  float f_pos=0.f, f_neg=0.f, f_obj=0.f, f_ce=0.f, f_sl1=0.f;

  if (n < N) {
    const int a = n % ANUM;
    const int w = (n/ANUM) % W;
    const int h = n/(ANUM*W);
    const float sz = (a==0)?0.08f:((a==1)?0.16f:0.28f);
    const float cx = ((float)w + 0.5f)/(float)W;
    const float cy = ((float)h + 0.5f)/(float)H;
    const float hs = sz*0.5f;
    const float ax0=cx-hs, ay0=cy-hs, ax1=cx+hs, ay1=cy+hs;
    const float areaA = (ax1-ax0)*(ay1-ay0);

    float best=-1.f; int midx=0;
    #pragma unroll
    for (int m=0;m<MNUM;m++){
      float bcx=sbox[4*m+0], bcy=sbox[4*m+1], bw=sbox[4*m+2], bh=sbox[4*m+3];
      float bx0=bcx-bw*0.5f, by0=bcy-bh*0.5f, bx1=bcx+bw*0.5f, by1=bcy+bh*0.5f;
      float iw=fminf(ax1,bx1)-fmaxf(ax0,bx0);
      float ih=fminf(ay1,by1)-fmaxf(ay0,by0);
      iw = fmaxf(iw, 0.f); ih = fmaxf(ih, 0.f);
      float inter=iw*ih;
      float areaB=(bx1-bx0)*(by1-by0);
      float iou = inter/(areaA+areaB-inter+1e-9f);
      if (iou > best){best=iou; midx=m;}
    }
    const bool pos = best >= 0.5f;
    const bool neg = best < 0.4f;

    const float* pb = pred + (size_t)b*CH*HW;
    const int pix = h*W + w;
    const int cb = a*8;
    const float obj = pb[(cb+4)*HW + pix];
    const float sp = log1pf(expf(-fabsf(obj)));
    const float obj_all = fmaxf(obj, 0.f) - (pos ? obj : 0.f) + sp;

    negvals[(size_t)b*N + n] = neg ? obj_all : -1.f;
    if (neg)
      atomicAdd(&g_hist[(size_t)(scale*BNUM + b)*NBIN + (__float_as_uint(obj_all) >> 19)], 1);

    if (pos) {
      f_pos = 1.f; f_obj = obj_all;
      int ct = slab[midx] - 1;
      ct = ct < 0 ? 0 : (ct > CNUM-1 ? CNUM-1 : ct);
      float c0 = pb[(cb+5)*HW+pix];
      float c1 = pb[(cb+6)*HW+pix];
      float c2 = pb[(cb+7)*HW+pix];
      float mx = fmaxf(c0, fmaxf(c1, c2));
      float lse = mx + logf(expf(c0-mx)+expf(c1-mx)+expf(c2-mx));
      float csel = (ct==0)?c0:((ct==1)?c1:c2);
      f_ce = lse - csel;
      float mcx=sbox[4*midx+0], mcy=sbox[4*midx+1], mw=sbox[4*midx+2], mh=sbox[4*midx+3];
      float t0=(mcx-cx)/sz, t1=(mcy-cy)/sz, t2=logf(mw/sz), t3=logf(mh/sz);
      float l0=pb[(cb+0)*HW+pix], l1=pb[(cb+1)*HW+pix], l2=pb[(cb+2)*HW+pix], l3=pb[(cb+3)*HW+pix];
      float ssum=0.f, d;
      d=fabsf(l0-t0); ssum += (d<1.f)?(0.5f*d*d):(d-0.5f);
      d=fabsf(l1-t1); ssum += (d<1.f)?(0.5f*d*d):(d-0.5f);
      d=fabsf(l2-t2); ssum += (d<1.f)?(0.5f*d*d):(d-0.5f);
      d=fabsf(l3-t3); ssum += (d<1.f)?(0.5f*d*d):(d-0.5f);
      f_sl1 = ssum;
    } else if (neg) {
      f_neg = 1.f;
    }
  }

  __shared__ float red[5][4];
  const int lane = threadIdx.x & 63, wv = threadIdx.x >> 6;
  float vals[5] = {f_pos, f_neg, f_obj, f_ce, f_sl1};
  #pragma unroll
  for (int q=0;q<5;q++){
    float r = wred(vals[q]);
    if (lane==0) red[q][wv] = r;
  }
  __syncthreads();
  if (threadIdx.x==0){
    float* ag = g_acc + (scale*BNUM + b)*5;
    #pragma unroll
    for (int q=0;q<5;q++){
      float t = red[q][0]+red[q][1]+red[q][2]+red[q][3];
      if (t != 0.f) atomicAdd(&ag[q], t);
    }
  }
}

// Find threshold bin T, in-bin rank kk, count above T. 96 blocks.
__global__ __launch_bounds__(256) void k2_pick(){
  const int g = blockIdx.x;
  const float* ag = g_acc + g*5;
  const float npos_f = ag[0], avail_f = ag[1];
  const int npos = (int)(npos_f + 0.5f);
  const int avail = (int)(avail_f + 0.5f);
  const int k = (npos==0) ? (avail < 100 ? avail : 100)
                          : (3*npos < avail ? 3*npos : avail);
  const int* hist = g_hist + (size_t)g*NBIN;

  __shared__ int tsum[256];
  __shared__ int s_tt, s_cum;

  // thread t covers bins [t*32, t*32+32)
  const int4* h4 = (const int4*)(hist + threadIdx.x*32);
  int ssum = 0;
  #pragma unroll
  for (int i=0;i<8;i++){ int4 v = h4[i]; ssum += v.x+v.y+v.z+v.w; }
  tsum[threadIdx.x] = ssum;
  __syncthreads();

  if (k > 0){
    if (threadIdx.x==0){
      int cum=0, tt=0;
      for (int t=255;t>=0;t--){
        if (cum + tsum[t] >= k){ tt=t; break; }
        cum += tsum[t];
      }
      s_tt = tt; s_cum = cum;
    }
    __syncthreads();
    if (threadIdx.x == s_tt){
      int cum = s_cum, T=0, kk=0;
      for (int j=31;j>=0;j--){
        int c = hist[s_tt*32 + j];
        if (cum + c >= k){ T = s_tt*32 + j; kk = k - cum; break; }
        cum += c;
      }
      g_T[g]=T; g_kk[g]=kk; g_cab[g]=cum;
    }
  } else if (threadIdx.x==0){
    g_T[g]=0x7FFFFFFF; g_kk[g]=0; g_cab[g]=0;
  }
}

// Full-width single pass: sum above-bin values, compact in-bin candidates.
__global__ __launch_bounds__(256) void k2_scan(const float* __restrict__ negvals){
  const int bid = blockIdx.x;            // 32*CPB = 672 blocks
  const int b = bid / CPB;
  const int c = bid % CPB;
  int s, ci;
  if (c < 16){ s = 0; ci = c; }
  else if (c < 20){ s = 1; ci = c - 16; }
  else { s = 2; ci = 0; }
  const int g = s*BNUM + b;
  const int N = (s==0) ? 76800 : ((s==1) ? 19200 : 4800);
  const size_t segbase = (s==0) ? 0
                       : ((s==1) ? (size_t)BNUM*76800
                                 : (size_t)BNUM*(76800+19200));
  const float* seg = negvals + segbase + (size_t)b*N + (size_t)ci*CHUNK;
  const int T = g_T[g];
  const int lane = threadIdx.x & 63;

  const float4* p4 = (const float4*)seg;
  float sab = 0.f;
  for (int i = threadIdx.x; i < CHUNK/4; i += 256){
    float4 v4 = p4[i];
    #pragma unroll
    for (int j=0;j<4;j++){
      float v = (&v4.x)[j];
      const bool val = (v >= 0.f);
      const int bin = (int)(__float_as_uint(v) >> 19);
      if (val && bin > T) sab += v;
      const bool isT = val && (bin == T);
      unsigned long long peers = __ballot(isT ? 1 : 0);
      if (isT){
        const int leader = __ffsll(peers) - 1;
        const int cnt = __popcll(peers);
        int base = 0;
        if (lane == leader) base = atomicAdd(&g_ccnt[g], cnt);
        base = __shfl(base, leader, 64);
        const int idx = base + (int)__popcll(peers & ((1ull<<lane)-1ull));
        if (idx < CAP) g_cand[(size_t)g*CAP + idx] = v;
      }
    }
  }

  __shared__ float red[4];
  float r = wred(sab);
  if (lane == 0) red[threadIdx.x>>6] = r;
  __syncthreads();
  if (threadIdx.x == 0){
    float t = red[0]+red[1]+red[2]+red[3];
    if (t != 0.f) atomicAdd(&g_sab[g], t);
  }
}

// Exact k-th-largest refinement over in-bin candidates + final loss. 96 blocks.
__global__ __launch_bounds__(256) void k2_fin(const float* __restrict__ negvals){
  const int g = blockIdx.x;
  const int s = g >> 5;
  const int b = g & 31;
  const int N = (s==0) ? 76800 : ((s==1) ? 19200 : 4800);
  const size_t segbase = (s==0) ? 0
                       : ((s==1) ? (size_t)BNUM*76800
                                 : (size_t)BNUM*(76800+19200));
  const float* seg = negvals + segbase + (size_t)b*N;

  const float* ag = g_acc + g*5;
  const float npos_f = ag[0], avail_f = ag[1];
  const int npos = (int)(npos_f + 0.5f);
  const int avail = (int)(avail_f + 0.5f);
  const int k = (npos==0) ? (avail < 100 ? avail : 100)
                          : (3*npos < avail ? 3*npos : avail);

  __shared__ float cv[CAP];
  __shared__ int hist[256];
  __shared__ int s_bin, s_rem;
  __shared__ float red[2][4];

  float ss = 0.f, ns = 0.f;
  float sab = 0.f, cab_f = 0.f;

  if (k > 0){
    const int T = g_T[g];
    const int kk0 = g_kk[g];
    const int cab = g_cab[g];
    sab = g_sab[g];
    cab_f = (float)cab;
    const int C = g_ccnt[g];

    unsigned prel = 0, pm = 0;
    int rem = kk0;

    if (C <= CAP){
      for (int i=threadIdx.x; i<C; i+=256) cv[i] = g_cand[(size_t)g*CAP + i];
      __syncthreads();
      #pragma unroll
      for (int p=0;p<3;p++){
        const int shift = (p==0)?11:((p==1)?3:0);
        const unsigned bmax = (p==2)?7u:255u;
        hist[threadIdx.x] = 0;
        __syncthreads();
        for (int i=threadIdx.x; i<C; i+=256){
          unsigned u19 = __float_as_uint(cv[i]) & 0x7FFFFu;
          if ((u19 & pm) == prel) atomicAdd(&hist[(u19>>shift)&bmax], 1);
        }
        __syncthreads();
        if (threadIdx.x==0){
          int cum=0;
          for (int j=(int)bmax;j>=0;j--){
            cum += hist[j];
            if (cum >= rem){ s_bin=j; s_rem = rem-(cum-hist[j]); break; }
          }
        }
        __syncthreads();
        prel |= ((unsigned)s_bin << shift);
        pm |= (bmax << shift);
        rem = s_rem;
        __syncthreads();
      }
      const float thr = __uint_as_float(((unsigned)T << 19) | prel);
      for (int i=threadIdx.x; i<C; i+=256){
        float v = cv[i];
        if (v >= thr){ ss += v; ns += 1.f; }
      }
    } else {
      // Overflow fallback (never on benign data): radix over seg from global.
      const float4* p4 = (const float4*)seg;
      const int N4 = N >> 2;
      #pragma unroll
      for (int p=0;p<3;p++){
        const int shift = (p==0)?11:((p==1)?3:0);
        const unsigned bmax = (p==2)?7u:255u;
        hist[threadIdx.x] = 0;
        __syncthreads();
        for (int i=threadIdx.x; i<N4; i+=256){
          float4 v4 = p4[i];
          #pragma unroll
          for (int j=0;j<4;j++){
            float v = (&v4.x)[j];
            if (v < 0.f) continue;
            unsigned u = __float_as_uint(v);
            if ((int)(u >> 19) != T) continue;
            unsigned u19 = u & 0x7FFFFu;
            if ((u19 & pm) == prel) atomicAdd(&hist[(u19>>shift)&bmax], 1);
          }
        }
        __syncthreads();
        if (threadIdx.x==0){
          int cum=0;
          for (int j=(int)bmax;j>=0;j--){
            cum += hist[j];
            if (cum >= rem){ s_bin=j; s_rem = rem-(cum-hist[j]); break; }
          }
        }
        __syncthreads();
        prel |= ((unsigned)s_bin << shift);
        pm |= (bmax << shift);
        rem = s_rem;
        __syncthreads();
      }
      const float thr = __uint_as_float(((unsigned)T << 19) | prel);
      for (int i=threadIdx.x; i<N4; i+=256){
        float4 v4 = p4[i];
        #pragma unroll
        for (int j=0;j<4;j++){
          float v = (&v4.x)[j];
          if (v < 0.f) continue;
          if ((int)(__float_as_uint(v) >> 19) == T && v >= thr){ ss += v; ns += 1.f; }
        }
      }
    }
  }

  const int lane = threadIdx.x & 63, wv = threadIdx.x >> 6;
  float r0 = wred(ss), r1 = wred(ns);
  if (lane==0){ red[0][wv]=r0; red[1][wv]=r1; }
  __syncthreads();
  if (threadIdx.x==0){
    float sstot = sab + red[0][0]+red[0][1]+red[0][2]+red[0][3];
    float nstot = cab_f + red[1][0]+red[1][1]+red[1][2]+red[1][3];
    float cnt = npos_f + nstot;
    float lo = (cnt > 0.f) ? (ag[2] + sstot)/cnt : 0.f;
    float lc = (npos > 0) ? ag[3]/npos_f : 0.f;
    float ll = (npos > 0) ? ag[4]/(npos_f*4.f) : 0.f;
    atomicAdd(&g_lsum[0], lo);
    atomicAdd(&g_lsum[1], lc);
    atomicAdd(&g_lsum[2], ll);
  }
}

__global__ __launch_bounds__(64) void kfin(float* out){
  if (threadIdx.x==0){
    float lo = g_lsum[0]*(1.f/32.f);
    float lc = g_lsum[1]*(1.f/32.f);
    float ll = g_lsum[2]*(1.f/32.f);
    out[0]=lo; out[1]=lc; out[2]=ll; out[3]=lo+lc+ll;
  }
}

extern "C" void kernel_launch(void* const* d_in, const int* in_sizes, int n_in,
                              void* d_out, int out_size, void* d_ws, size_t ws_size,
                              hipStream_t stream)
{
  const float* pred0 = (const float*)d_in[0];
  const float* pred1 = (const float*)d_in[1];
  const float* pred2 = (const float*)d_in[2];
  const float* boxes = (const float*)d_in[6];
  const int*   labels = (const int*)d_in[7];
  float* out = (float*)d_out;

  float* negvals = (float*)d_ws;   // 3,225,600 floats = 12.9 MB (only ws use)

  kinit<<<768, 256, 0, stream>>>();
  k1_scan<<<dim3(300,32), 256, 0, stream>>>(pred0, boxes, labels, negvals, 160,160, 0);
  k1_scan<<<dim3(75,32),  256, 0, stream>>>(pred1, boxes, labels, negvals + (size_t)BNUM*76800, 80,80, 1);
  k1_scan<<<dim3(19,32),  256, 0, stream>>>(pred2, boxes, labels, negvals + (size_t)BNUM*(76800+19200), 40,40, 2);
  k2_pick<<<96, 256, 0, stream>>>();
  k2_scan<<<672, 256, 0, stream>>>(negvals);
  k2_fin<<<96, 256, 0, stream>>>(negvals);
  kfin<<<1, 64, 0, stream>>>(out);
}

// Round 4
// 364.915 us; speedup vs baseline: 1.7879x; 1.7879x over previous
//
#include <hip/hip_runtime.h>
#include <math.h>

#define ANUM 3
#define CNUM 3
#define BNUM 32
#define MNUM 16
#define CH 24      // ANUM*(5+CNUM)
#define NBIN 8192  // 13-bit float-top-bits histogram (sign=0 for all values)
#define NSEG 96
#define CAP 8192   // max in-threshold-bin candidates kept (worst real ~2K)
#define CHUNK 4800 // elements per chunk; divides 76800/19200/4800
#define CPB 21     // chunks per batch image: 16 + 4 + 1

// All small state in static device memory -> workspace holds ONLY negvals.
__device__ __align__(16) int   g_hist[NSEG*NBIN];
__device__ __align__(16) float g_cand[(size_t)NSEG*CAP];
__device__ int   g_ccnt[NSEG];
__device__ int   g_T[NSEG];
__device__ int   g_kk[NSEG];
__device__ int   g_cab[NSEG];   // count strictly above bin T
__device__ float g_sab[NSEG];   // sum of values strictly above bin T
__device__ float g_acc[NSEG*5];
__device__ float g_lsum[3];

__device__ __forceinline__ float wred(float v){
  #pragma unroll
  for (int off=32; off; off>>=1) v += __shfl_down(v, off, 64);
  return v;
}
__device__ __forceinline__ int wredi(int v){
  #pragma unroll
  for (int off=32; off; off>>=1) v += __shfl_down(v, off, 64);
  return v;
}

__device__ __forceinline__ void seg_map(int c, int& s, int& ci){
  if (c < 16){ s = 0; ci = c; }
  else if (c < 20){ s = 1; ci = c - 16; }
  else { s = 2; ci = 0; }
}
__device__ __forceinline__ void seg_geom(int s, int& N, size_t& segbase){
  N = (s==0) ? 76800 : ((s==1) ? 19200 : 4800);
  segbase = (s==0) ? 0
          : ((s==1) ? (size_t)BNUM*76800
                    : (size_t)BNUM*(76800+19200));
}

__global__ __launch_bounds__(256) void kinit(){
  const int gid = blockIdx.x*256 + threadIdx.x;   // 768*256 = 196608
  ((int4*)g_hist)[gid] = make_int4(0,0,0,0);      // 196608*4 = NSEG*NBIN
  if (gid < NSEG*5) g_acc[gid] = 0.f;
  if (gid < 3) g_lsum[gid] = 0.f;
  if (gid < NSEG){ g_ccnt[gid]=0; g_sab[gid]=0.f; }
}

__global__ __launch_bounds__(256) void k1_scan(
    const float* __restrict__ pred, const float* __restrict__ boxes,
    const int* __restrict__ labels, float* __restrict__ negvals,
    int H, int W, int scale)
{
  const int b = blockIdx.y;
  const int N = H*W*ANUM;
  const int HW = H*W;
  const int n = blockIdx.x*256 + threadIdx.x;

  __shared__ float sbox[MNUM*4];
  __shared__ int slab[MNUM];
  if (threadIdx.x < MNUM*4) sbox[threadIdx.x] = boxes[b*MNUM*4 + threadIdx.x];
  else if (threadIdx.x < MNUM*5) slab[threadIdx.x - MNUM*4] = labels[b*MNUM + (threadIdx.x - MNUM*4)];
  __syncthreads();

  float f_pos=0.f, f_neg=0.f, f_obj=0.f, f_ce=0.f, f_sl1=0.f;

  if (n < N) {
    const int a = n % ANUM;
    const int w = (n/ANUM) % W;
    const int h = n/(ANUM*W);
    const float sz = (a==0)?0.08f:((a==1)?0.16f:0.28f);
    const float cx = ((float)w + 0.5f)/(float)W;
    const float cy = ((float)h + 0.5f)/(float)H;
    const float hs = sz*0.5f;
    const float ax0=cx-hs, ay0=cy-hs, ax1=cx+hs, ay1=cy+hs;
    const float areaA = (ax1-ax0)*(ay1-ay0);

    float best=-1.f; int midx=0;
    #pragma unroll
    for (int m=0;m<MNUM;m++){
      float bcx=sbox[4*m+0], bcy=sbox[4*m+1], bw=sbox[4*m+2], bh=sbox[4*m+3];
      float bx0=bcx-bw*0.5f, by0=bcy-bh*0.5f, bx1=bcx+bw*0.5f, by1=bcy+bh*0.5f;
      float iw=fminf(ax1,bx1)-fmaxf(ax0,bx0);
      float ih=fminf(ay1,by1)-fmaxf(ay0,by0);
      iw = fmaxf(iw, 0.f); ih = fmaxf(ih, 0.f);
      float inter=iw*ih;
      float areaB=(bx1-bx0)*(by1-by0);
      float iou = inter/(areaA+areaB-inter+1e-9f);
      if (iou > best){best=iou; midx=m;}
    }
    const bool pos = best >= 0.5f;
    const bool neg = best < 0.4f;

    const float* pb = pred + (size_t)b*CH*HW;
    const int pix = h*W + w;
    const int cb = a*8;
    const float obj = pb[(cb+4)*HW + pix];
    const float sp = log1pf(expf(-fabsf(obj)));
    const float obj_all = fmaxf(obj, 0.f) - (pos ? obj : 0.f) + sp;

    negvals[(size_t)b*N + n] = neg ? obj_all : -1.f;

    if (pos) {
      f_pos = 1.f; f_obj = obj_all;
      int ct = slab[midx] - 1;
      ct = ct < 0 ? 0 : (ct > CNUM-1 ? CNUM-1 : ct);
      float c0 = pb[(cb+5)*HW+pix];
      float c1 = pb[(cb+6)*HW+pix];
      float c2 = pb[(cb+7)*HW+pix];
      float mx = fmaxf(c0, fmaxf(c1, c2));
      float lse = mx + logf(expf(c0-mx)+expf(c1-mx)+expf(c2-mx));
      float csel = (ct==0)?c0:((ct==1)?c1:c2);
      f_ce = lse - csel;
      float mcx=sbox[4*midx+0], mcy=sbox[4*midx+1], mw=sbox[4*midx+2], mh=sbox[4*midx+3];
      float t0=(mcx-cx)/sz, t1=(mcy-cy)/sz, t2=logf(mw/sz), t3=logf(mh/sz);
      float l0=pb[(cb+0)*HW+pix], l1=pb[(cb+1)*HW+pix], l2=pb[(cb+2)*HW+pix], l3=pb[(cb+3)*HW+pix];
      float ssum=0.f, d;
      d=fabsf(l0-t0); ssum += (d<1.f)?(0.5f*d*d):(d-0.5f);
      d=fabsf(l1-t1); ssum += (d<1.f)?(0.5f*d*d):(d-0.5f);
      d=fabsf(l2-t2); ssum += (d<1.f)?(0.5f*d*d):(d-0.5f);
      d=fabsf(l3-t3); ssum += (d<1.f)?(0.5f*d*d):(d-0.5f);
      f_sl1 = ssum;
    } else if (neg) {
      f_neg = 1.f;
    }
  }

  __shared__ float red[5][4];
  const int lane = threadIdx.x & 63, wv = threadIdx.x >> 6;
  float vals[5] = {f_pos, f_neg, f_obj, f_ce, f_sl1};
  #pragma unroll
  for (int q=0;q<5;q++){
    float r = wred(vals[q]);
    if (lane==0) red[q][wv] = r;
  }
  __syncthreads();
  if (threadIdx.x==0){
    float* ag = g_acc + (scale*BNUM + b)*5;
    #pragma unroll
    for (int q=0;q<5;q++){
      float t = red[q][0]+red[q][1]+red[q][2]+red[q][3];
      if (t != 0.f) atomicAdd(&ag[q], t);
    }
  }
}

// Per-block LDS-privatized histogram over negvals; flush nonzero bins.
// Per-global-address contributor chain <= 16 blocks (vs 76800 before).
__global__ __launch_bounds__(256) void khist(const float* __restrict__ negvals){
  const int bid = blockIdx.x;            // 32*CPB = 672 blocks
  const int b = bid / CPB;
  int s, ci; seg_map(bid % CPB, s, ci);
  const int g = s*BNUM + b;
  int N; size_t segbase; seg_geom(s, N, segbase);
  const float* seg = negvals + segbase + (size_t)b*N + (size_t)ci*CHUNK;

  __shared__ int lh[NBIN];               // 32 KB
  int4* lh4 = (int4*)lh;
  for (int i=threadIdx.x; i<NBIN/4; i+=256) lh4[i] = make_int4(0,0,0,0);
  __syncthreads();

  const float4* p4 = (const float4*)seg;
  for (int i=threadIdx.x; i<CHUNK/4; i+=256){
    float4 v4 = p4[i];
    #pragma unroll
    for (int j=0;j<4;j++){
      float v = (&v4.x)[j];
      if (v >= 0.f) atomicAdd(&lh[__float_as_uint(v) >> 19], 1);
    }
  }
  __syncthreads();

  int* gh = g_hist + (size_t)g*NBIN;
  for (int i=threadIdx.x; i<NBIN/4; i+=256){
    int4 h = lh4[i];
    if (h.x) atomicAdd(gh + i*4 + 0, h.x);
    if (h.y) atomicAdd(gh + i*4 + 1, h.y);
    if (h.z) atomicAdd(gh + i*4 + 2, h.z);
    if (h.w) atomicAdd(gh + i*4 + 3, h.w);
  }
}

// Find threshold bin T, in-bin rank kk, count above T. 96 blocks.
__global__ __launch_bounds__(256) void k2_pick(){
  const int g = blockIdx.x;
  const float* ag = g_acc + g*5;
  const float npos_f = ag[0], avail_f = ag[1];
  const int npos = (int)(npos_f + 0.5f);
  const int avail = (int)(avail_f + 0.5f);
  const int k = (npos==0) ? (avail < 100 ? avail : 100)
                          : (3*npos < avail ? 3*npos : avail);
  const int* hist = g_hist + (size_t)g*NBIN;

  __shared__ int tsum[256];
  __shared__ int s_tt, s_cum;

  const int4* h4 = (const int4*)(hist + threadIdx.x*32);
  int ssum = 0;
  #pragma unroll
  for (int i=0;i<8;i++){ int4 v = h4[i]; ssum += v.x+v.y+v.z+v.w; }
  tsum[threadIdx.x] = ssum;
  __syncthreads();

  if (k > 0){
    if (threadIdx.x==0){
      int cum=0, tt=0;
      for (int t=255;t>=0;t--){
        if (cum + tsum[t] >= k){ tt=t; break; }
        cum += tsum[t];
      }
      s_tt = tt; s_cum = cum;
    }
    __syncthreads();
    if (threadIdx.x == s_tt){
      int cum = s_cum, T=0, kk=0;
      for (int j=31;j>=0;j--){
        int c = hist[s_tt*32 + j];
        if (cum + c >= k){ T = s_tt*32 + j; kk = k - cum; break; }
        cum += c;
      }
      g_T[g]=T; g_kk[g]=kk; g_cab[g]=cum;
    }
  } else if (threadIdx.x==0){
    g_T[g]=0x7FFFFFFF; g_kk[g]=0; g_cab[g]=0;
  }
}

// Full-width pass: sum above-bin values; compact in-bin candidates with
// block-aggregated offsets (ONE global return-atomic per block).
__global__ __launch_bounds__(256) void k2_scan(const float* __restrict__ negvals){
  const int bid = blockIdx.x;            // 672 blocks
  const int b = bid / CPB;
  int s, ci; seg_map(bid % CPB, s, ci);
  const int g = s*BNUM + b;
  int N; size_t segbase; seg_geom(s, N, segbase);
  const float* seg = negvals + segbase + (size_t)b*N + (size_t)ci*CHUNK;
  const int T = g_T[g];
  const int lane = threadIdx.x & 63;

  const float4* p4 = (const float4*)seg;
  float sab = 0.f; int cnt = 0;

  // Pass A: count in-bin, sum above-bin.
  for (int i = threadIdx.x; i < CHUNK/4; i += 256){
    float4 v4 = p4[i];
    #pragma unroll
    for (int j=0;j<4;j++){
      float v = (&v4.x)[j];
      if (v < 0.f) continue;
      const int bin = (int)(__float_as_uint(v) >> 19);
      if (bin > T) sab += v;
      else if (bin == T) cnt++;
    }
  }

  __shared__ float redf[4];
  __shared__ int   redi[4];
  __shared__ int   s_base, s_loc;
  float r = wred(sab); int c = wredi(cnt);
  if (lane == 0){ redf[threadIdx.x>>6] = r; redi[threadIdx.x>>6] = c; }
  __syncthreads();
  if (threadIdx.x == 0){
    float t = redf[0]+redf[1]+redf[2]+redf[3];
    int   n = redi[0]+redi[1]+redi[2]+redi[3];
    if (t != 0.f) atomicAdd(&g_sab[g], t);
    s_base = (n > 0) ? atomicAdd(&g_ccnt[g], n) : 0;
    s_loc = 0;
  }
  __syncthreads();
  const int base = s_base;

  // Pass B: compact in-bin values (chunk is L2-hot; order irrelevant).
  if (__syncthreads_count(cnt > 0) == 0) return;  // no in-bin in this block
  for (int i = threadIdx.x; i < CHUNK/4; i += 256){
    float4 v4 = p4[i];
    #pragma unroll
    for (int j=0;j<4;j++){
      float v = (&v4.x)[j];
      const bool isT = (v >= 0.f) && ((int)(__float_as_uint(v) >> 19) == T);
      unsigned long long peers = __ballot(isT ? 1 : 0);
      if (isT){
        const int leader = __ffsll(peers) - 1;
        int wbase = 0;
        if (lane == leader) wbase = atomicAdd(&s_loc, (int)__popcll(peers));
        wbase = __shfl(wbase, leader, 64);
        const int idx = base + wbase + (int)__popcll(peers & ((1ull<<lane)-1ull));
        if (idx < CAP) g_cand[(size_t)g*CAP + idx] = v;
      }
    }
  }
}

// Exact k-th-largest refinement over in-bin candidates + final loss. 96 blocks.
__global__ __launch_bounds__(256) void k2_fin(const float* __restrict__ negvals){
  const int g = blockIdx.x;
  const int s = g >> 5;
  const int b = g & 31;
  int N; size_t segbase; seg_geom(s, N, segbase);
  const float* seg = negvals + segbase + (size_t)b*N;

  const float* ag = g_acc + g*5;
  const float npos_f = ag[0], avail_f = ag[1];
  const int npos = (int)(npos_f + 0.5f);
  const int avail = (int)(avail_f + 0.5f);
  const int k = (npos==0) ? (avail < 100 ? avail : 100)
                          : (3*npos < avail ? 3*npos : avail);

  __shared__ float cv[CAP];
  __shared__ int hist[256];
  __shared__ int s_bin, s_rem;
  __shared__ float red[2][4];

  float ss = 0.f, ns = 0.f;
  float sab = 0.f, cab_f = 0.f;

  if (k > 0){
    const int T = g_T[g];
    const int kk0 = g_kk[g];
    const int cab = g_cab[g];
    sab = g_sab[g];
    cab_f = (float)cab;
    const int C = g_ccnt[g];

    unsigned prel = 0, pm = 0;
    int rem = kk0;

    if (C <= CAP){
      for (int i=threadIdx.x; i<C; i+=256) cv[i] = g_cand[(size_t)g*CAP + i];
      __syncthreads();
      #pragma unroll
      for (int p=0;p<3;p++){
        const int shift = (p==0)?11:((p==1)?3:0);
        const unsigned bmax = (p==2)?7u:255u;
        hist[threadIdx.x] = 0;
        __syncthreads();
        for (int i=threadIdx.x; i<C; i+=256){
          unsigned u19 = __float_as_uint(cv[i]) & 0x7FFFFu;
          if ((u19 & pm) == prel) atomicAdd(&hist[(u19>>shift)&bmax], 1);
        }
        __syncthreads();
        if (threadIdx.x==0){
          int cum=0;
          for (int j=(int)bmax;j>=0;j--){
            cum += hist[j];
            if (cum >= rem){ s_bin=j; s_rem = rem-(cum-hist[j]); break; }
          }
        }
        __syncthreads();
        prel |= ((unsigned)s_bin << shift);
        pm |= (bmax << shift);
        rem = s_rem;
        __syncthreads();
      }
      const float thr = __uint_as_float(((unsigned)T << 19) | prel);
      for (int i=threadIdx.x; i<C; i+=256){
        float v = cv[i];
        if (v >= thr){ ss += v; ns += 1.f; }
      }
    } else {
      // Overflow fallback (not expected on benign data): radix over seg.
      const float4* p4 = (const float4*)seg;
      const int N4 = N >> 2;
      #pragma unroll
      for (int p=0;p<3;p++){
        const int shift = (p==0)?11:((p==1)?3:0);
        const unsigned bmax = (p==2)?7u:255u;
        hist[threadIdx.x] = 0;
        __syncthreads();
        for (int i=threadIdx.x; i<N4; i+=256){
          float4 v4 = p4[i];
          #pragma unroll
          for (int j=0;j<4;j++){
            float v = (&v4.x)[j];
            if (v < 0.f) continue;
            unsigned u = __float_as_uint(v);
            if ((int)(u >> 19) != T) continue;
            unsigned u19 = u & 0x7FFFFu;
            if ((u19 & pm) == prel) atomicAdd(&hist[(u19>>shift)&bmax], 1);
          }
        }
        __syncthreads();
        if (threadIdx.x==0){
          int cum=0;
          for (int j=(int)bmax;j>=0;j--){
            cum += hist[j];
            if (cum >= rem){ s_bin=j; s_rem = rem-(cum-hist[j]); break; }
          }
        }
        __syncthreads();
        prel |= ((unsigned)s_bin << shift);
        pm |= (bmax << shift);
        rem = s_rem;
        __syncthreads();
      }
      const float thr = __uint_as_float(((unsigned)T << 19) | prel);
      for (int i=threadIdx.x; i<N4; i+=256){
        float4 v4 = p4[i];
        #pragma unroll
        for (int j=0;j<4;j++){
          float v = (&v4.x)[j];
          if (v < 0.f) continue;
          if ((int)(__float_as_uint(v) >> 19) == T && v >= thr){ ss += v; ns += 1.f; }
        }
      }
    }
  }

  const int lane = threadIdx.x & 63, wv = threadIdx.x >> 6;
  float r0 = wred(ss), r1 = wred(ns);
  if (lane==0){ red[0][wv]=r0; red[1][wv]=r1; }
  __syncthreads();
  if (threadIdx.x==0){
    float sstot = sab + red[0][0]+red[0][1]+red[0][2]+red[0][3];
    float nstot = cab_f + red[1][0]+red[1][1]+red[1][2]+red[1][3];
    float cnt = npos_f + nstot;
    float lo = (cnt > 0.f) ? (ag[2] + sstot)/cnt : 0.f;
    float lc = (npos > 0) ? ag[3]/npos_f : 0.f;
    float ll = (npos > 0) ? ag[4]/(npos_f*4.f) : 0.f;
    atomicAdd(&g_lsum[0], lo);
    atomicAdd(&g_lsum[1], lc);
    atomicAdd(&g_lsum[2], ll);
  }
}

__global__ __launch_bounds__(64) void kfin(float* out){
  if (threadIdx.x==0){
    float lo = g_lsum[0]*(1.f/32.f);
    float lc = g_lsum[1]*(1.f/32.f);
    float ll = g_lsum[2]*(1.f/32.f);
    out[0]=lo; out[1]=lc; out[2]=ll; out[3]=lo+lc+ll;
  }
}

extern "C" void kernel_launch(void* const* d_in, const int* in_sizes, int n_in,
                              void* d_out, int out_size, void* d_ws, size_t ws_size,
                              hipStream_t stream)
{
  const float* pred0 = (const float*)d_in[0];
  const float* pred1 = (const float*)d_in[1];
  const float* pred2 = (const float*)d_in[2];
  const float* boxes = (const float*)d_in[6];
  const int*   labels = (const int*)d_in[7];
  float* out = (float*)d_out;

  float* negvals = (float*)d_ws;   // 3,225,600 floats = 12.9 MB (only ws use)

  kinit<<<768, 256, 0, stream>>>();
  k1_scan<<<dim3(300,32), 256, 0, stream>>>(pred0, boxes, labels, negvals, 160,160, 0);
  k1_scan<<<dim3(75,32),  256, 0, stream>>>(pred1, boxes, labels, negvals + (size_t)BNUM*76800, 80,80, 1);
  k1_scan<<<dim3(19,32),  256, 0, stream>>>(pred2, boxes, labels, negvals + (size_t)BNUM*(76800+19200), 40,40, 2);
  khist<<<672, 256, 0, stream>>>(negvals);
  k2_pick<<<96, 256, 0, stream>>>();
  k2_scan<<<672, 256, 0, stream>>>(negvals);
  k2_fin<<<96, 256, 0, stream>>>(negvals);
  kfin<<<1, 64, 0, stream>>>(out);
}

// Round 5
// 232.055 us; speedup vs baseline: 2.8115x; 1.5725x over previous
//
#include <hip/hip_runtime.h>
#include <math.h>

#define ANUM 3
#define CNUM 3
#define BNUM 32
#define MNUM 16
#define CH 24      // ANUM*(5+CNUM)
#define NBIN 4096  // 12-bit float-top-bits histogram (sign=0 for all values)
#define NSEG 96
#define CAP 8192   // max in-threshold-bin candidates kept
#define CHUNK 4800 // elements per chunk; divides 76800/19200/4800
#define CPB 21     // chunks per batch image: 16 + 4 + 1

// All small state in static device memory -> workspace holds ONLY negvals.
__device__ __align__(16) int   g_hist[NSEG*NBIN];
__device__ __align__(16) float g_cand[(size_t)NSEG*CAP];
__device__ int   g_ccnt[NSEG];
__device__ int   g_T[NSEG];
__device__ int   g_kk[NSEG];
__device__ int   g_cab[NSEG];   // count strictly above bin T
__device__ float g_sab[NSEG];   // sum of values strictly above bin T
__device__ float g_acc[NSEG*5];
__device__ float g_lsum[3];
__device__ int   g_done;

__device__ __forceinline__ float wred(float v){
  #pragma unroll
  for (int off=32; off; off>>=1) v += __shfl_down(v, off, 64);
  return v;
}
__device__ __forceinline__ int wredi(int v){
  #pragma unroll
  for (int off=32; off; off>>=1) v += __shfl_down(v, off, 64);
  return v;
}

__device__ __forceinline__ void seg_map(int c, int& s, int& ci){
  if (c < 16){ s = 0; ci = c; }
  else if (c < 20){ s = 1; ci = c - 16; }
  else { s = 2; ci = 0; }
}
__device__ __forceinline__ void seg_geom(int s, int& N, size_t& segbase){
  N = (s==0) ? 76800 : ((s==1) ? 19200 : 4800);
  segbase = (s==0) ? 0
          : ((s==1) ? (size_t)BNUM*76800
                    : (size_t)BNUM*(76800+19200));
}

__global__ __launch_bounds__(256) void kinit(){
  const int gid = blockIdx.x*256 + threadIdx.x;   // 384*256 = 98304
  ((int4*)g_hist)[gid] = make_int4(0,0,0,0);      // 98304*4 = NSEG*NBIN
  if (gid < NSEG*5) g_acc[gid] = 0.f;
  if (gid < 3) g_lsum[gid] = 0.f;
  if (gid == 3) g_done = 0;
  if (gid < NSEG){ g_ccnt[gid]=0; g_sab[gid]=0.f; }
}

// One thread per PIXEL: 3 anchors in registers, shared box corners,
// divide-free argmax (cross-multiplication), one divide per anchor at end
// (same operands/order as reference -> bit-identical best/thresholds).
template<int H, int W, int SCALE>
__device__ __forceinline__ void k1_work(
    const float* __restrict__ pred, float* __restrict__ negvals,
    const float* sbox, const int* slab, int b, int pix, int* lh, float* f)
{
  constexpr int HW = H*W;
  constexpr int N = HW*ANUM;
  constexpr size_t segbase = (SCALE==0) ? 0
                           : ((SCALE==1) ? (size_t)BNUM*76800
                                         : (size_t)BNUM*(76800+19200));
  const bool valid = (pix < HW);
  const int pp = valid ? pix : 0;
  const int h = pp / W, w = pp % W;
  const float cx = ((float)w + 0.5f)/(float)W;
  const float cy = ((float)h + 0.5f)/(float)H;

  const float* pb = pred + (size_t)b*CH*HW;
  float obj[3];
  #pragma unroll
  for (int a=0;a<3;a++) obj[a] = pb[(a*8+4)*HW + pp];   // coalesced

  float ax0[3],ay0[3],ax1[3],ay1[3],areaA[3];
  #pragma unroll
  for (int a=0;a<3;a++){
    const float sz=(a==0)?0.08f:((a==1)?0.16f:0.28f);
    const float hs=sz*0.5f;
    ax0[a]=cx-hs; ay0[a]=cy-hs; ax1[a]=cx+hs; ay1[a]=cy+hs;
    areaA[a]=(ax1[a]-ax0[a])*(ay1[a]-ay0[a]);
  }
  float bi[3]={-1.f,-1.f,-1.f}, bu[3]={1.f,1.f,1.f};
  int bm[3]={0,0,0};
  #pragma unroll
  for (int m=0;m<MNUM;m++){
    const float bcx=sbox[4*m], bcy=sbox[4*m+1], bw=sbox[4*m+2], bh=sbox[4*m+3];
    const float bx0=bcx-bw*0.5f, by0=bcy-bh*0.5f, bx1=bcx+bw*0.5f, by1=bcy+bh*0.5f;
    const float areaB=(bx1-bx0)*(by1-by0);
    #pragma unroll
    for (int a=0;a<3;a++){
      float iw=fminf(ax1[a],bx1)-fmaxf(ax0[a],bx0);
      float ih=fminf(ay1[a],by1)-fmaxf(ay0[a],by0);
      iw=fmaxf(iw,0.f); ih=fmaxf(ih,0.f);
      const float inter=iw*ih;
      const float uni=areaA[a]+areaB-inter+1e-9f;
      // iou_new > iou_best  <=>  inter*bu > bi*uni   (uni,bu > 0)
      if (inter*bu[a] > bi[a]*uni){ bi[a]=inter; bu[a]=uni; bm[a]=m; }
    }
  }
  #pragma unroll
  for (int a=0;a<3;a++){
    const float best = bi[a]/bu[a];       // same operands as reference iou
    const bool pos = best >= 0.5f;
    const bool neg = best < 0.4f;
    const float o = obj[a];
    const float sp = log1pf(expf(-fabsf(o)));
    const float obj_all = fmaxf(o,0.f) - (pos? o:0.f) + sp;
    if (valid){
      negvals[segbase + (size_t)b*N + pp*3 + a] = neg ? obj_all : -1.f;
      if (neg){
        atomicAdd(&lh[__float_as_uint(obj_all)>>20], 1);
        f[1] += 1.f;
      }
      if (pos){
        f[0]+=1.f; f[2]+=obj_all;
        const int midx=bm[a];
        int ct = slab[midx]-1; ct = ct<0?0:(ct>CNUM-1?CNUM-1:ct);
        const int cb=a*8;
        float c0=pb[(cb+5)*HW+pp], c1=pb[(cb+6)*HW+pp], c2=pb[(cb+7)*HW+pp];
        float mx=fmaxf(c0,fmaxf(c1,c2));
        float lse=mx+logf(expf(c0-mx)+expf(c1-mx)+expf(c2-mx));
        float csel=(ct==0)?c0:((ct==1)?c1:c2);
        f[3]+=lse-csel;
        const float sz=(a==0)?0.08f:((a==1)?0.16f:0.28f);
        float mcx=sbox[4*midx],mcy=sbox[4*midx+1],mw=sbox[4*midx+2],mh=sbox[4*midx+3];
        float t0=(mcx-cx)/sz,t1=(mcy-cy)/sz,t2=logf(mw/sz),t3=logf(mh/sz);
        float l0=pb[(cb+0)*HW+pp],l1=pb[(cb+1)*HW+pp],l2=pb[(cb+2)*HW+pp],l3=pb[(cb+3)*HW+pp];
        float ssum=0.f,d;
        d=fabsf(l0-t0); ssum+=(d<1.f)?(0.5f*d*d):(d-0.5f);
        d=fabsf(l1-t1); ssum+=(d<1.f)?(0.5f*d*d):(d-0.5f);
        d=fabsf(l2-t2); ssum+=(d<1.f)?(0.5f*d*d):(d-0.5f);
        d=fabsf(l3-t3); ssum+=(d<1.f)?(0.5f*d*d):(d-0.5f);
        f[4]+=ssum;
      }
    }
  }
}

// Merged over all 3 scales; LDS-private histogram fused in.
__global__ __launch_bounds__(256) void k1_all(
    const float* __restrict__ pred0, const float* __restrict__ pred1,
    const float* __restrict__ pred2, const float* __restrict__ boxes,
    const int* __restrict__ labels, float* __restrict__ negvals)
{
  __shared__ float sbox[MNUM*4];
  __shared__ int   slab[MNUM];
  __shared__ int   lh[NBIN];          // 16 KB
  __shared__ float red[5][4];

  const int b = blockIdx.y;
  if (threadIdx.x < MNUM*4) sbox[threadIdx.x] = boxes[b*MNUM*4 + threadIdx.x];
  else if (threadIdx.x < MNUM*5) slab[threadIdx.x - MNUM*4] = labels[b*MNUM + (threadIdx.x - MNUM*4)];
  int4* lh4 = (int4*)lh;
  for (int i=threadIdx.x; i<NBIN/4; i+=256) lh4[i] = make_int4(0,0,0,0);
  __syncthreads();

  const int c = blockIdx.x;   // 0..131 : 100 s0 + 25 s1 + 7 s2
  float f[5] = {0.f,0.f,0.f,0.f,0.f};
  int g;
  if (c < 100){ g = b;          k1_work<160,160,0>(pred0, negvals, sbox, slab, b, c*256 + (int)threadIdx.x, lh, f); }
  else if (c < 125){ g = BNUM + b; k1_work<80,80,1>(pred1, negvals, sbox, slab, b, (c-100)*256 + (int)threadIdx.x, lh, f); }
  else { g = 2*BNUM + b;        k1_work<40,40,2>(pred2, negvals, sbox, slab, b, (c-125)*256 + (int)threadIdx.x, lh, f); }

  const int lane = threadIdx.x & 63, wv = threadIdx.x >> 6;
  #pragma unroll
  for (int q=0;q<5;q++){
    float r = wred(f[q]);
    if (lane==0) red[q][wv] = r;
  }
  __syncthreads();                       // also orders all lh atomics
  if (threadIdx.x < 5){
    const int q = threadIdx.x;
    float t = red[q][0]+red[q][1]+red[q][2]+red[q][3];
    if (t != 0.f) atomicAdd(&g_acc[g*5+q], t);
  }
  int* gh = g_hist + (size_t)g*NBIN;
  for (int i=threadIdx.x; i<NBIN/4; i+=256){
    int4 hv = lh4[i];
    if (hv.x) atomicAdd(gh + i*4 + 0, hv.x);
    if (hv.y) atomicAdd(gh + i*4 + 1, hv.y);
    if (hv.z) atomicAdd(gh + i*4 + 2, hv.z);
    if (hv.w) atomicAdd(gh + i*4 + 3, hv.w);
  }
}

// Find threshold bin T, in-bin rank kk, count above T. 96 blocks.
__global__ __launch_bounds__(256) void k2_pick(){
  const int g = blockIdx.x;
  const float* ag = g_acc + g*5;
  const float npos_f = ag[0], avail_f = ag[1];
  const int npos = (int)(npos_f + 0.5f);
  const int avail = (int)(avail_f + 0.5f);
  const int k = (npos==0) ? (avail < 100 ? avail : 100)
                          : (3*npos < avail ? 3*npos : avail);
  const int* hist = g_hist + (size_t)g*NBIN;

  __shared__ int tsum[256];
  __shared__ int s_tt, s_cum;

  // thread t covers bins [t*16, t*16+16)
  const int4* h4 = (const int4*)(hist + threadIdx.x*16);
  int ssum = 0;
  #pragma unroll
  for (int i=0;i<4;i++){ int4 v = h4[i]; ssum += v.x+v.y+v.z+v.w; }
  tsum[threadIdx.x] = ssum;
  __syncthreads();

  if (k > 0){
    if (threadIdx.x==0){
      int cum=0, tt=0;
      for (int t=255;t>=0;t--){
        if (cum + tsum[t] >= k){ tt=t; break; }
        cum += tsum[t];
      }
      s_tt = tt; s_cum = cum;
    }
    __syncthreads();
    if (threadIdx.x == s_tt){
      int cum = s_cum, T=0, kk=0;
      for (int j=15;j>=0;j--){
        int c = hist[s_tt*16 + j];
        if (cum + c >= k){ T = s_tt*16 + j; kk = k - cum; break; }
        cum += c;
      }
      g_T[g]=T; g_kk[g]=kk; g_cab[g]=cum;
    }
  } else if (threadIdx.x==0){
    g_T[g]=0x7FFFFFFF; g_kk[g]=0; g_cab[g]=0;
  }
}

// Full-width pass: sum above-bin values; compact in-bin candidates with
// block-aggregated offsets (ONE global return-atomic per block).
__global__ __launch_bounds__(256) void k2_scan(const float* __restrict__ negvals){
  const int bid = blockIdx.x;            // 672 blocks
  const int b = bid / CPB;
  int s, ci; seg_map(bid % CPB, s, ci);
  const int g = s*BNUM + b;
  int N; size_t segbase; seg_geom(s, N, segbase);
  const float* seg = negvals + segbase + (size_t)b*N + (size_t)ci*CHUNK;
  const int T = g_T[g];
  const int lane = threadIdx.x & 63;

  const float4* p4 = (const float4*)seg;
  float sab = 0.f; int cnt = 0;

  for (int i = threadIdx.x; i < CHUNK/4; i += 256){
    float4 v4 = p4[i];
    #pragma unroll
    for (int j=0;j<4;j++){
      float v = (&v4.x)[j];
      if (v < 0.f) continue;
      const int bin = (int)(__float_as_uint(v) >> 20);
      if (bin > T) sab += v;
      else if (bin == T) cnt++;
    }
  }

  __shared__ float redf[4];
  __shared__ int   redi[4];
  __shared__ int   s_base, s_loc;
  float r = wred(sab); int c = wredi(cnt);
  if (lane == 0){ redf[threadIdx.x>>6] = r; redi[threadIdx.x>>6] = c; }
  __syncthreads();
  if (threadIdx.x == 0){
    float t = redf[0]+redf[1]+redf[2]+redf[3];
    int   n = redi[0]+redi[1]+redi[2]+redi[3];
    if (t != 0.f) atomicAdd(&g_sab[g], t);
    s_base = (n > 0) ? atomicAdd(&g_ccnt[g], n) : 0;
    s_loc = 0;
  }
  __syncthreads();
  const int base = s_base;

  if (__syncthreads_count(cnt > 0) == 0) return;
  for (int i = threadIdx.x; i < CHUNK/4; i += 256){
    float4 v4 = p4[i];
    #pragma unroll
    for (int j=0;j<4;j++){
      float v = (&v4.x)[j];
      const bool isT = (v >= 0.f) && ((int)(__float_as_uint(v) >> 20) == T);
      unsigned long long peers = __ballot(isT ? 1 : 0);
      if (isT){
        const int leader = __ffsll(peers) - 1;
        int wbase = 0;
        if (lane == leader) wbase = atomicAdd(&s_loc, (int)__popcll(peers));
        wbase = __shfl(wbase, leader, 64);
        const int idx = base + wbase + (int)__popcll(peers & ((1ull<<lane)-1ull));
        if (idx < CAP) g_cand[(size_t)g*CAP + idx] = v;
      }
    }
  }
}

// Exact k-th-largest refinement (low 20 bits) + final loss + fused output. 96 blocks.
__global__ __launch_bounds__(256) void k2_fin(const float* __restrict__ negvals, float* __restrict__ out){
  const int g = blockIdx.x;
  const int s = g >> 5;
  const int b = g & 31;
  int N; size_t segbase; seg_geom(s, N, segbase);
  const float* seg = negvals + segbase + (size_t)b*N;

  const float* ag = g_acc + g*5;
  const float npos_f = ag[0], avail_f = ag[1];
  const int npos = (int)(npos_f + 0.5f);
  const int avail = (int)(avail_f + 0.5f);
  const int k = (npos==0) ? (avail < 100 ? avail : 100)
                          : (3*npos < avail ? 3*npos : avail);

  __shared__ float cv[CAP];
  __shared__ int hist[256];
  __shared__ int s_bin, s_rem;
  __shared__ float red[2][4];

  float ss = 0.f, ns = 0.f;
  float sab = 0.f, cab_f = 0.f;

  if (k > 0){
    const int T = g_T[g];
    const int kk0 = g_kk[g];
    const int cab = g_cab[g];
    sab = g_sab[g];
    cab_f = (float)cab;
    const int C = g_ccnt[g];

    unsigned prel = 0, pm = 0;
    int rem = kk0;

    if (C <= CAP){
      for (int i=threadIdx.x; i<C; i+=256) cv[i] = g_cand[(size_t)g*CAP + i];
      __syncthreads();
      #pragma unroll
      for (int p=0;p<3;p++){
        const int shift = (p==0)?12:((p==1)?4:0);
        const unsigned bmax = (p==2)?15u:255u;
        hist[threadIdx.x] = 0;
        __syncthreads();
        for (int i=threadIdx.x; i<C; i+=256){
          unsigned u20 = __float_as_uint(cv[i]) & 0xFFFFFu;
          if ((u20 & pm) == prel) atomicAdd(&hist[(u20>>shift)&bmax], 1);
        }
        __syncthreads();
        if (threadIdx.x==0){
          int cum=0;
          for (int j=(int)bmax;j>=0;j--){
            cum += hist[j];
            if (cum >= rem){ s_bin=j; s_rem = rem-(cum-hist[j]); break; }
          }
        }
        __syncthreads();
        prel |= ((unsigned)s_bin << shift);
        pm |= (bmax << shift);
        rem = s_rem;
        __syncthreads();
      }
      const float thr = __uint_as_float(((unsigned)T << 20) | prel);
      for (int i=threadIdx.x; i<C; i+=256){
        float v = cv[i];
        if (v >= thr){ ss += v; ns += 1.f; }
      }
    } else {
      // Overflow fallback: radix over the segment from global.
      const float4* p4 = (const float4*)seg;
      const int N4 = N >> 2;
      #pragma unroll
      for (int p=0;p<3;p++){
        const int shift = (p==0)?12:((p==1)?4:0);
        const unsigned bmax = (p==2)?15u:255u;
        hist[threadIdx.x] = 0;
        __syncthreads();
        for (int i=threadIdx.x; i<N4; i+=256){
          float4 v4 = p4[i];
          #pragma unroll
          for (int j=0;j<4;j++){
            float v = (&v4.x)[j];
            if (v < 0.f) continue;
            unsigned u = __float_as_uint(v);
            if ((int)(u >> 20) != T) continue;
            unsigned u20 = u & 0xFFFFFu;
            if ((u20 & pm) == prel) atomicAdd(&hist[(u20>>shift)&bmax], 1);
          }
        }
        __syncthreads();
        if (threadIdx.x==0){
          int cum=0;
          for (int j=(int)bmax;j>=0;j--){
            cum += hist[j];
            if (cum >= rem){ s_bin=j; s_rem = rem-(cum-hist[j]); break; }
          }
        }
        __syncthreads();
        prel |= ((unsigned)s_bin << shift);
        pm |= (bmax << shift);
        rem = s_rem;
        __syncthreads();
      }
      const float thr = __uint_as_float(((unsigned)T << 20) | prel);
      for (int i=threadIdx.x; i<N4; i+=256){
        float4 v4 = p4[i];
        #pragma unroll
        for (int j=0;j<4;j++){
          float v = (&v4.x)[j];
          if (v < 0.f) continue;
          if ((int)(__float_as_uint(v) >> 20) == T && v >= thr){ ss += v; ns += 1.f; }
        }
      }
    }
  }

  const int lane = threadIdx.x & 63, wv = threadIdx.x >> 6;
  float r0 = wred(ss), r1 = wred(ns);
  if (lane==0){ red[0][wv]=r0; red[1][wv]=r1; }
  __syncthreads();
  if (threadIdx.x==0){
    float sstot = sab + red[0][0]+red[0][1]+red[0][2]+red[0][3];
    float nstot = cab_f + red[1][0]+red[1][1]+red[1][2]+red[1][3];
    float cnt = npos_f + nstot;
    float lo = (cnt > 0.f) ? (ag[2] + sstot)/cnt : 0.f;
    float lc = (npos > 0) ? ag[3]/npos_f : 0.f;
    float ll = (npos > 0) ? ag[4]/(npos_f*4.f) : 0.f;
    atomicAdd(&g_lsum[0], lo);
    atomicAdd(&g_lsum[1], lc);
    atomicAdd(&g_lsum[2], ll);
    __threadfence();
    if (atomicAdd(&g_done, 1) == NSEG-1){
      float L0 = atomicAdd(&g_lsum[0], 0.f);   // coherent reads
      float L1 = atomicAdd(&g_lsum[1], 0.f);
      float L2 = atomicAdd(&g_lsum[2], 0.f);
      float lo2 = L0*(1.f/32.f), lc2 = L1*(1.f/32.f), ll2 = L2*(1.f/32.f);
      out[0]=lo2; out[1]=lc2; out[2]=ll2; out[3]=lo2+lc2+ll2;
    }
  }
}

extern "C" void kernel_launch(void* const* d_in, const int* in_sizes, int n_in,
                              void* d_out, int out_size, void* d_ws, size_t ws_size,
                              hipStream_t stream)
{
  const float* pred0 = (const float*)d_in[0];
  const float* pred1 = (const float*)d_in[1];
  const float* pred2 = (const float*)d_in[2];
  const float* boxes = (const float*)d_in[6];
  const int*   labels = (const int*)d_in[7];
  float* out = (float*)d_out;

  float* negvals = (float*)d_ws;   // 3,225,600 floats = 12.9 MB (only ws use)

  kinit<<<384, 256, 0, stream>>>();
  k1_all<<<dim3(132,32), 256, 0, stream>>>(pred0, pred1, pred2, boxes, labels, negvals);
  k2_pick<<<96, 256, 0, stream>>>();
  k2_scan<<<672, 256, 0, stream>>>(negvals);
  k2_fin<<<96, 256, 0, stream>>>(negvals, out);
}